// Round 2
// baseline (484.370 us; speedup 1.0000x reference)
//
#include <hip/hip_runtime.h>

#define CROP 14
#define MAXBS 64
#define NLVL 4
#define BDIM 4
#define NBOX 128
#define CCH 256
#define C4 (CCH / 4)   // 64 float4 per pixel

// Kernel A: per-batch rank scan -> slot_map + output1.
// grid = B (4), block = 256 (one thread per (lvl,slot) pair).
__global__ void roi_meta_kernel(const float* __restrict__ db,
                                int* __restrict__ slot_map,
                                float* __restrict__ out1) {
    int b = blockIdx.x;
    int t = threadIdx.x;            // 0..255 = lvl*64 + slot
    __shared__ int lvl_arr[NBOX];
    __shared__ int smap[NLVL * MAXBS];

    if (t < NBOX) {
        lvl_arr[t] = (int)db[(b * NBOX + t) * 7 + 0];  // ids: exact 0.0..3.0
    }
    smap[t] = -1;
    __syncthreads();

    if (t < NLVL) {
        int r = 0;
        for (int n = 0; n < NBOX; ++n) {
            if (lvl_arr[n] == t) {
                if (r < MAXBS) smap[t * MAXBS + r] = n;
                r++;  // rank keeps counting; >=64 dropped
            }
        }
    }
    __syncthreads();

    int n = smap[t];
    int lvl = t >> 6;
    int slot = t & 63;
    slot_map[(lvl * BDIM + b) * MAXBS + slot] = n;

    // output1: [B, NLVL*MAXBS, 6], level-concatenated along axis 1
    float* o = out1 + ((size_t)(b * (NLVL * MAXBS) + t)) * 6;
    if (n >= 0) {
        const float* src = db + (b * NBOX + n) * 7 + 1;  // cx,cy,w,h,cls,conf
        #pragma unroll
        for (int j = 0; j < 6; ++j) o[j] = src[j];
    } else {
        #pragma unroll
        for (int j = 0; j < 6; ++j) o[j] = 0.f;
    }
}

// Kernel B: one block per slot (lvl,b,slot). 256 threads = 4 waves.
// Wave w handles y-rows {w, w+4, w+8, ...}; lane = float4 channel group.
// All loads/stores are 16 B/lane fully coalesced (1 KB per wave op).
__global__ __launch_bounds__(256) void roi_crop_kernel(
        const float* __restrict__ f0,
        const float* __restrict__ f1,
        const float* __restrict__ f2,
        const float* __restrict__ f3,
        const float* __restrict__ db,
        const int* __restrict__ slot_map,
        float* __restrict__ out0) {
    int sl = blockIdx.x;            // lvl*256 + b*64 + slot, 0..1023
    float4* outb = (float4*)(out0 + (size_t)sl * (CROP * CROP * CCH));

    int n = slot_map[sl];
    if (n < 0) {
        float4 z = make_float4(0.f, 0.f, 0.f, 0.f);
        for (int i = threadIdx.x; i < CROP * CROP * C4; i += 256) outb[i] = z;
        return;
    }

    int lvl = sl >> 8;
    int b   = (sl >> 6) & 3;
    int s   = 256 >> lvl;           // fmap H == W
    const float4* f = (const float4*)((lvl == 0) ? f0 : (lvl == 1) ? f1
                                    : (lvl == 2) ? f2 : f3);

    const float* bx = db + (b * NBOX + n) * 7;
    float cx = bx[1], cy = bx[2], w = bx[3], h = bx[4];

    // normalized box, matching reference fp32 op order
    float y1n = (cy - h * 0.5f) / 1023.0f;
    float x1n = (cx - w * 0.5f) / 1023.0f;
    float y2n = (cy + h * 0.5f) / 1023.0f;
    float x2n = (cx + w * 0.5f) / 1023.0f;

    float Hm1    = (float)(s - 1);
    float ybase  = y1n * Hm1;
    float yscale = (y2n - y1n) * Hm1;
    float xbase  = x1n * Hm1;
    float xscale = (x2n - x1n) * Hm1;

    int wave = threadIdx.x >> 6;
    int lane = threadIdx.x & 63;

    for (int y = wave; y < CROP; y += 4) {
        float ty = (float)y / 13.0f;
        float ys = ybase + ty * yscale;
        float y0f = floorf(ys);
        float wy = ys - y0f;
        int iy0 = (int)y0f;
        iy0 = iy0 < 0 ? 0 : (iy0 > s - 1 ? s - 1 : iy0);
        int iy1 = iy0 + 1;
        if (iy1 > s - 1) iy1 = s - 1;
        bool vy = (ys >= 0.f) && (ys <= Hm1);

        const float4* rowT = f + ((size_t)(b * s + iy0)) * s * C4;
        const float4* rowB = f + ((size_t)(b * s + iy1)) * s * C4;
        float omwy = 1.f - wy;
        float4* orow = outb + y * (CROP * C4);

        #pragma unroll
        for (int x = 0; x < CROP; ++x) {
            float tx = (float)x / 13.0f;
            float xs = xbase + tx * xscale;
            float x0f = floorf(xs);
            float wx = xs - x0f;
            int ix0 = (int)x0f;
            ix0 = ix0 < 0 ? 0 : (ix0 > s - 1 ? s - 1 : ix0);
            int ix1 = ix0 + 1;
            if (ix1 > s - 1) ix1 = s - 1;
            bool v = vy && (xs >= 0.f) && (xs <= Hm1);

            float4 a  = rowT[ix0 * C4 + lane];
            float4 bb = rowT[ix1 * C4 + lane];
            float4 cc = rowB[ix0 * C4 + lane];
            float4 dd = rowB[ix1 * C4 + lane];

            float omwx = 1.f - wx;
            float4 r;
            r.x = (a.x * omwx + bb.x * wx) * omwy + (cc.x * omwx + dd.x * wx) * wy;
            r.y = (a.y * omwx + bb.y * wx) * omwy + (cc.y * omwx + dd.y * wx) * wy;
            r.z = (a.z * omwx + bb.z * wx) * omwy + (cc.z * omwx + dd.z * wx) * wy;
            r.w = (a.w * omwx + bb.w * wx) * omwy + (cc.w * omwx + dd.w * wx) * wy;
            if (!v) r = make_float4(0.f, 0.f, 0.f, 0.f);

            orow[x * C4 + lane] = r;
        }
    }
}

extern "C" void kernel_launch(void* const* d_in, const int* in_sizes, int n_in,
                              void* d_out, int out_size, void* d_ws, size_t ws_size,
                              hipStream_t stream) {
    const float* f0 = (const float*)d_in[0];
    const float* f1 = (const float*)d_in[1];
    const float* f2 = (const float*)d_in[2];
    const float* f3 = (const float*)d_in[3];
    const float* db = (const float*)d_in[4];
    // d_in[5] = images, only shape (1024x1024) is used -> hardcoded

    float* out0 = (float*)d_out;
    float* out1 = out0 + (size_t)NLVL * BDIM * MAXBS * CROP * CROP * CCH;
    int* slot_map = (int*)d_ws;     // 4 KB

    roi_meta_kernel<<<BDIM, 256, 0, stream>>>(db, slot_map, out1);
    roi_crop_kernel<<<NLVL * BDIM * MAXBS, 256, 0, stream>>>(
        f0, f1, f2, f3, db, slot_map, out0);
}

// Round 3
// 476.479 us; speedup vs baseline: 1.0166x; 1.0166x over previous
//
#include <hip/hip_runtime.h>

#define CROP 14
#define MAXBS 64
#define NLVL 4
#define BDIM 4
#define NBOX 128
#define CCH 256
#define C4 (CCH / 4)   // 64 float4 per pixel

// Kernel A: per-batch rank scan -> slot_map + output1.
// grid = B (4), block = 256 (one thread per (lvl,slot) pair).
__global__ void roi_meta_kernel(const float* __restrict__ db,
                                int* __restrict__ slot_map,
                                float* __restrict__ out1) {
    int b = blockIdx.x;
    int t = threadIdx.x;            // 0..255 = lvl*64 + slot
    __shared__ int lvl_arr[NBOX];
    __shared__ int smap[NLVL * MAXBS];

    if (t < NBOX) {
        lvl_arr[t] = (int)db[(b * NBOX + t) * 7 + 0];  // ids: exact 0.0..3.0
    }
    smap[t] = -1;
    __syncthreads();

    if (t < NLVL) {
        int r = 0;
        for (int n = 0; n < NBOX; ++n) {
            if (lvl_arr[n] == t) {
                if (r < MAXBS) smap[t * MAXBS + r] = n;
                r++;  // rank keeps counting; >=64 dropped
            }
        }
    }
    __syncthreads();

    int n = smap[t];
    int lvl = t >> 6;
    int slot = t & 63;
    slot_map[(lvl * BDIM + b) * MAXBS + slot] = n;

    // output1: [B, NLVL*MAXBS, 6], level-concatenated along axis 1
    float* o = out1 + ((size_t)(b * (NLVL * MAXBS) + t)) * 6;
    if (n >= 0) {
        const float* src = db + (b * NBOX + n) * 7 + 1;  // cx,cy,w,h,cls,conf
        #pragma unroll
        for (int j = 0; j < 6; ++j) o[j] = src[j];
    } else {
        #pragma unroll
        for (int j = 0; j < 6; ++j) o[j] = 0.f;
    }
}

// Kernel B: grid = 1024 slots x 4 row-groups = 4096 blocks, 256 thr = 4 waves.
// Block (sl, g): wave w handles output row y = g + 4*w (rows 14,15 skipped).
// lane = float4 channel group -> every load/store is 16 B/lane, 1 KB/wave-op.
// 16384 waves total: 2x wave-slot oversubscription, fine-grained balance.
__global__ __launch_bounds__(256) void roi_crop_kernel(
        const float* __restrict__ f0,
        const float* __restrict__ f1,
        const float* __restrict__ f2,
        const float* __restrict__ f3,
        const float* __restrict__ db,
        const int* __restrict__ slot_map,
        float* __restrict__ out0) {
    int bid = blockIdx.x;
    int g   = bid & 3;              // row group
    int sl  = bid >> 2;             // lvl*256 + b*64 + slot, 0..1023
    int wave = threadIdx.x >> 6;
    int lane = threadIdx.x & 63;
    int y = g + 4 * wave;           // output row for this wave
    if (y >= CROP) return;

    float4* outb = (float4*)(out0 + (size_t)sl * (CROP * CROP * CCH));
    float4* orow = outb + y * (CROP * C4);

    int n = slot_map[sl];
    if (n < 0) {
        float4 z = make_float4(0.f, 0.f, 0.f, 0.f);
        #pragma unroll
        for (int x = 0; x < CROP; ++x) orow[x * C4 + lane] = z;
        return;
    }

    int lvl = sl >> 8;
    int b   = (sl >> 6) & 3;
    int s   = 256 >> lvl;           // fmap H == W
    const float4* f = (const float4*)((lvl == 0) ? f0 : (lvl == 1) ? f1
                                    : (lvl == 2) ? f2 : f3);

    const float* bx = db + (b * NBOX + n) * 7;
    float cx = bx[1], cy = bx[2], w = bx[3], h = bx[4];

    // normalized box, matching reference fp32 op order
    float y1n = (cy - h * 0.5f) / 1023.0f;
    float x1n = (cx - w * 0.5f) / 1023.0f;
    float y2n = (cy + h * 0.5f) / 1023.0f;
    float x2n = (cx + w * 0.5f) / 1023.0f;

    float Hm1    = (float)(s - 1);
    float ybase  = y1n * Hm1;
    float yscale = (y2n - y1n) * Hm1;
    float xbase  = x1n * Hm1;
    float xscale = (x2n - x1n) * Hm1;

    float ty = (float)y / 13.0f;
    float ys = ybase + ty * yscale;
    float y0f = floorf(ys);
    float wy = ys - y0f;
    int iy0 = (int)y0f;
    iy0 = iy0 < 0 ? 0 : (iy0 > s - 1 ? s - 1 : iy0);
    int iy1 = iy0 + 1;
    if (iy1 > s - 1) iy1 = s - 1;
    bool vy = (ys >= 0.f) && (ys <= Hm1);

    const float4* rowT = f + ((size_t)(b * s + iy0)) * s * C4;
    const float4* rowB = f + ((size_t)(b * s + iy1)) * s * C4;
    float omwy = 1.f - wy;

    #pragma unroll
    for (int x = 0; x < CROP; ++x) {
        float tx = (float)x / 13.0f;
        float xs = xbase + tx * xscale;
        float x0f = floorf(xs);
        float wx = xs - x0f;
        int ix0 = (int)x0f;
        ix0 = ix0 < 0 ? 0 : (ix0 > s - 1 ? s - 1 : ix0);
        int ix1 = ix0 + 1;
        if (ix1 > s - 1) ix1 = s - 1;
        bool v = vy && (xs >= 0.f) && (xs <= Hm1);

        float4 a  = rowT[ix0 * C4 + lane];
        float4 bb = rowT[ix1 * C4 + lane];
        float4 cc = rowB[ix0 * C4 + lane];
        float4 dd = rowB[ix1 * C4 + lane];

        float omwx = 1.f - wx;
        float4 r;
        r.x = (a.x * omwx + bb.x * wx) * omwy + (cc.x * omwx + dd.x * wx) * wy;
        r.y = (a.y * omwx + bb.y * wx) * omwy + (cc.y * omwx + dd.y * wx) * wy;
        r.z = (a.z * omwx + bb.z * wx) * omwy + (cc.z * omwx + dd.z * wx) * wy;
        r.w = (a.w * omwx + bb.w * wx) * omwy + (cc.w * omwx + dd.w * wx) * wy;
        if (!v) r = make_float4(0.f, 0.f, 0.f, 0.f);

        orow[x * C4 + lane] = r;
    }
}

extern "C" void kernel_launch(void* const* d_in, const int* in_sizes, int n_in,
                              void* d_out, int out_size, void* d_ws, size_t ws_size,
                              hipStream_t stream) {
    const float* f0 = (const float*)d_in[0];
    const float* f1 = (const float*)d_in[1];
    const float* f2 = (const float*)d_in[2];
    const float* f3 = (const float*)d_in[3];
    const float* db = (const float*)d_in[4];
    // d_in[5] = images, only shape (1024x1024) is used -> hardcoded

    float* out0 = (float*)d_out;
    float* out1 = out0 + (size_t)NLVL * BDIM * MAXBS * CROP * CROP * CCH;
    int* slot_map = (int*)d_ws;     // 4 KB

    roi_meta_kernel<<<BDIM, 256, 0, stream>>>(db, slot_map, out1);
    roi_crop_kernel<<<NLVL * BDIM * MAXBS * 4, 256, 0, stream>>>(
        f0, f1, f2, f3, db, slot_map, out0);
}